// Round 17
// baseline (186.632 us; speedup 1.0000x reference)
//
#include <hip/hip_runtime.h>
#include <hip/hip_bf16.h>

#define SEQLEN  2048
#define DMODEL  1024
#define NHEADS  16
#define BT_ROWS 8192

typedef __attribute__((ext_vector_type(8))) _Float16 half8;
typedef __attribute__((ext_vector_type(4))) _Float16 half4;
typedef __attribute__((ext_vector_type(2))) _Float16 half2v;
typedef __attribute__((ext_vector_type(4))) float f32x4;
typedef unsigned short u16;

#define MFMAH(A, B, C)  __builtin_amdgcn_mfma_f32_16x16x32_f16((A), (B), (C), 0, 0, 0)

static __device__ __forceinline__ float fast_exp2(float x) {
#if __has_builtin(__builtin_amdgcn_exp2f)
    return __builtin_amdgcn_exp2f(x);
#else
    return exp2f(x);
#endif
}

// async global->LDS 16B
typedef const __attribute__((address_space(1))) unsigned int* gas_t;
typedef __attribute__((address_space(3))) unsigned int* las_t;
static __device__ __forceinline__ void gld16(const void* g, void* l) {
    __builtin_amdgcn_global_load_lds((gas_t)g, (las_t)l, 16, 0, 0);
}

// pack two f32 -> one u32 of 2 x f16 (RTZ)
static __device__ __forceinline__ unsigned pack_f16x2(float a, float b) {
    return __builtin_bit_cast(unsigned, __builtin_amdgcn_cvt_pkrtz(a, b));
}

// ---------------------------------------------------------------------------
// fused fp32 -> f16 conversion of x, w_qkv, w_out (one launch)
// ---------------------------------------------------------------------------
#define N4_X  (BT_ROWS * DMODEL / 4)          // 2097152
#define N4_WQ (3072 * 1024 / 4)               // 786432
#define N4_WO (1024 * 1024 / 4)               // 262144

__global__ __launch_bounds__(256)
void cvt_all(const float* __restrict__ x, const float* __restrict__ wq,
             const float* __restrict__ wo, u16* __restrict__ xF,
             u16* __restrict__ wqF, u16* __restrict__ woF)
{
    const int total = N4_X + N4_WQ + N4_WO;
    int i = blockIdx.x * 256 + threadIdx.x;
    const int stride = gridDim.x * 256;
    for (; i < total; i += stride) {
        const float* src;
        u16* dst;
        int idx;
        if (i < N4_X)               { src = x;  dst = xF;  idx = i; }
        else if (i < N4_X + N4_WQ)  { src = wq; dst = wqF; idx = i - N4_X; }
        else                        { src = wo; dst = woF; idx = i - N4_X - N4_WQ; }
        const float4 v = ((const float4*)src)[idx];
        const float f[4] = {v.x, v.y, v.z, v.w};
        ushort4 h4;
        u16 hh[4];
#pragma unroll
        for (int j = 0; j < 4; ++j)
            hh[j] = __builtin_bit_cast(u16, (_Float16)f[j]);
        h4.x = hh[0]; h4.y = hh[1]; h4.z = hh[2]; h4.w = hh[3];
        *(ushort4*)(dst + (size_t)idx * 4) = h4;
    }
}

// ---------------------------------------------------------------------------
// f16 MFMA GEMM — m97 fragment structure + T4 counted-vmcnt pipeline
// (unchanged from R16 green: 2-deep prefetch, vmcnt(4), raw barriers).
// ---------------------------------------------------------------------------
template<int MODE>
__global__ __launch_bounds__(256)
void gemm_nt_mfma(const u16* __restrict__ Af, const u16* __restrict__ Bf,
                  const float* __restrict__ bias, float* __restrict__ Cf,
                  u16* __restrict__ Pq, u16* __restrict__ Pk,
                  u16* __restrict__ Pv)
{
    __shared__ _Float16 Ah[2][128 * 32];
    __shared__ _Float16 Bh[2][128 * 32];

    const int tid  = threadIdx.x;
    const int lane = tid & 63;
    const int w    = tid >> 6;
    const int l15  = lane & 15;
    const int lg   = lane >> 4;
    const int wm   = w & 1;
    const int wn   = w >> 1;
    const int rowBase = blockIdx.y * 128;
    const int colBase = blockIdx.x * 128;

    const int srow = lane >> 2;
    const int sc   = lane & 3;

    f32x4 acc[4][4];
#pragma unroll
    for (int m = 0; m < 4; ++m)
#pragma unroll
        for (int n = 0; n < 4; ++n) acc[m][n] = (f32x4){0.f, 0.f, 0.f, 0.f};

    auto stage = [&](int kt) {
        const int p  = kt & 1;
        const int k0 = kt * 32;
#pragma unroll
        for (int i = 0; i < 2; ++i) {
            const int slab = w * 2 + i;
            const int row  = slab * 16 + srow;
            const int gc   = sc ^ ((row >> 1) & 3);
            const size_t aoff = (size_t)(rowBase + row) * 1024 + k0 + gc * 8;
            const size_t boff = (size_t)(colBase + row) * 1024 + k0 + gc * 8;
            gld16(Af + aoff, &Ah[p][slab * 512]);
            gld16(Bf + boff, &Bh[p][slab * 512]);
        }
    };

    stage(0);
    stage(1);

    for (int kt = 0; kt < 32; ++kt) {
        const int p = kt & 1;

        // barrier 1: my tile-kt loads done (counted; t+1 stays in flight)
        if (kt < 31) {
            asm volatile("s_waitcnt vmcnt(4)" ::: "memory");
        } else {
            asm volatile("s_waitcnt vmcnt(0)" ::: "memory");
        }
        __builtin_amdgcn_s_barrier();

        half8 afh[4], bfh[4];
#pragma unroll
        for (int m = 0; m < 4; ++m) {
            const int row = wm * 64 + m * 16 + l15;
            const int cR  = lg ^ ((row >> 1) & 3);
            afh[m] = *(const half8*)&Ah[p][row * 32 + cR * 8];
        }
#pragma unroll
        for (int n = 0; n < 4; ++n) {
            const int row = wn * 64 + n * 16 + l15;
            const int cR  = lg ^ ((row >> 1) & 3);
            bfh[n] = *(const half8*)&Bh[p][row * 32 + cR * 8];
        }

        // frags in regs before anyone overwrites buf p (rule 18 fence)
        asm volatile("s_waitcnt lgkmcnt(0)" ::: "memory");
        __builtin_amdgcn_sched_barrier(0);
        __builtin_amdgcn_s_barrier();     // barrier 2: all waves' reads done

        if (kt < 30) stage(kt + 2);       // overwrite buf p for tile kt+2

        __builtin_amdgcn_s_setprio(1);
#pragma unroll
        for (int m = 0; m < 4; ++m)
#pragma unroll
            for (int n = 0; n < 4; ++n)
                acc[m][n] = MFMAH(afh[m], bfh[n], acc[m][n]);
        __builtin_amdgcn_s_setprio(0);
    }

    float bv[4];
#pragma unroll
    for (int n = 0; n < 4; ++n)
        bv[n] = bias[colBase + wn * 64 + n * 16 + l15];

    if constexpr (MODE == 0) {
#pragma unroll
        for (int m = 0; m < 4; ++m)
#pragma unroll
            for (int n = 0; n < 4; ++n) {
                const int col = colBase + wn * 64 + n * 16 + l15;
#pragma unroll
                for (int r = 0; r < 4; ++r) {
                    const int row = rowBase + wm * 64 + m * 16 + lg * 4 + r;
                    Cf[(size_t)row * 1024 + col] = acc[m][n][r] + bv[n];
                }
            }
    } else {
        const int comp = colBase >> 10;                  // 0=Q 1=K 2=V
        const float scale = (comp == 0) ? (0.125f * 1.44269504f) : 1.0f;
        u16* hp = (comp == 0) ? Pq : ((comp == 1) ? Pk : Pv);
        const int colc0 = colBase & 1023;
#pragma unroll
        for (int m = 0; m < 4; ++m)
#pragma unroll
            for (int n = 0; n < 4; ++n) {
                const int col = colc0 + wn * 64 + n * 16 + l15;
#pragma unroll
                for (int r = 0; r < 4; ++r) {
                    const int row = rowBase + wm * 64 + m * 16 + lg * 4 + r;
                    const float v = (acc[m][n][r] + bv[n]) * scale;
                    hp[(size_t)row * 1024 + col] =
                        __builtin_bit_cast(u16, (_Float16)v);
                }
            }
    }
}

// ---------------------------------------------------------------------------
// f16 MFMA flash attention — R10/R15 proven structure. ONE change vs the
// green R16 file: the per-qt s_setprio(1)/(0) brackets in the QK loop are
// REMOVED. Theory: setprio is a side-effecting op that pins program order,
// so qt-chain k's exp2/pack block could not overlap qt-chain k+1's MFMA
// issue within the wave (m141: order-pinning defeats the scheduler). With
// only 2 waves/SIMD, within-wave overlap of the 4 independent qt chains is
// the remaining latency-hiding lever. Pure scheduling change - zero
// correctness risk. PV cluster keeps its setprio pair (matches R10 green).
// ---------------------------------------------------------------------------
__global__ __launch_bounds__(256, 2)
void flash_attn_mfma(const u16* __restrict__ Qf, const u16* __restrict__ Kf,
                     const u16* __restrict__ Vf, u16* __restrict__ Of)
{
    __shared__ __align__(16) _Float16 Kh[64 * 64];
    __shared__ __align__(16) _Float16 Vt[64][72];
    __shared__ __align__(16) _Float16 Pl[4][64][72];

    const int tid  = threadIdx.x;
    const int lane = tid & 63;
    const int w    = tid >> 6;
    const int l15  = lane & 15;
    const int lg   = lane >> 4;

    // 512 blocks: 8 XCDs x 64 -> 8 heads x 8 q-blocks per XCD
    const int raw = blockIdx.x;
    const int swz = (raw & 7) * 64 + (raw >> 3);
    const int bh  = swz >> 3;          // 0..63
    const int qb  = swz & 7;           // 0..7
    const int b   = bh >> 4;
    const int h   = bh & 15;

    const int qRow0 = b * SEQLEN + qb * 256 + w * 64;   // wave's q base
    const int kRowB = b * SEQLEN;
    const int hc    = h * 64;

    // ---- Q fragments (4 qt tiles of 16 rows), already scaled ----
    half8 Qr[4][2];
#pragma unroll
    for (int qt = 0; qt < 4; ++qt)
#pragma unroll
        for (int g = 0; g < 2; ++g) {
            const size_t off = (size_t)(qRow0 + qt * 16 + l15) * 1024
                             + hc + g * 32 + lg * 8;
            Qr[qt][g] = *(const half8*)(Qf + off);
        }

    f32x4 O[4][4];
    f32x4 accL[4];                     // lsum via ones-MFMA
#pragma unroll
    for (int qt = 0; qt < 4; ++qt) {
        accL[qt] = (f32x4){0.f, 0.f, 0.f, 0.f};
#pragma unroll
        for (int dt = 0; dt < 4; ++dt) O[qt][dt] = (f32x4){0.f, 0.f, 0.f, 0.f};
    }
    half8 vones;
#pragma unroll
    for (int j = 0; j < 8; ++j) vones[j] = (_Float16)1.0f;

    // V loader: rows (kv0, kv0+16) share (kv&15) -> adjacent permuted cols
    const int vp  = tid & 31;
    const int kv0 = (vp & 15) | ((vp >> 4) << 5);     // {0..15} u {32..47}
    const int pcol = (kv0 & 15) * 4 + (kv0 >> 4);     // even; pair at +1
    const int d0  = (tid >> 5) * 8;                   // 0..56

    // staged-tile registers (live across compute: T14)
    half8 kreg[2], vreg0, vreg1;
    int krow[2], kcc[2];

    auto load_tile = [&](int kt) {
#pragma unroll
        for (int i = 0; i < 2; ++i) {
            const int s = tid + 256 * i;
            const int row = s >> 3;
            const int c   = s & 7;
            krow[i] = row; kcc[i] = c;
            const int gc = c ^ (row & 7);
            const size_t g = (size_t)(kRowB + kt * 64 + row) * 1024 + hc + gc * 8;
            kreg[i] = *(const half8*)(Kf + g);
        }
        const size_t g = (size_t)(kRowB + kt * 64 + kv0) * 1024 + hc + d0;
        vreg0 = *(const half8*)(Vf + g);
        vreg1 = *(const half8*)(Vf + g + (size_t)16 * 1024);
    };

    load_tile(0);

    for (int kt = 0; kt < SEQLEN / 64; ++kt) {
        __syncthreads();   // previous tile's LDS reads complete
#pragma unroll
        for (int i = 0; i < 2; ++i)
            *(half8*)&Kh[krow[i] * 64 + kcc[i] * 8] = kreg[i];
#pragma unroll
        for (int j = 0; j < 8; ++j) {
            half2v pv;
            pv[0] = vreg0[j]; pv[1] = vreg1[j];
            *(half2v*)&Vt[d0 + j][pcol] = pv;
        }
        __syncthreads();   // staging visible

        if (kt < SEQLEN / 64 - 1) load_tile(kt + 1);   // overlaps compute below

        // ---- K fragments once (shared across all 4 qt) ----
        half8 kf[4][2];
#pragma unroll
        for (int k4 = 0; k4 < 4; ++k4) {
            const int row = k4 * 16 + l15;
            const int swk = row & 7;
            kf[k4][0] = *(const half8*)&Kh[row * 64 + ((lg     ^ swk) * 8)];
            kf[k4][1] = *(const half8*)&Kh[row * 64 + (((4+lg) ^ swk) * 8)];
        }

        // ---- per qt: S = (Q*log2e/8)K^T, p = 2^S, pack, b64 store ----
        // (no setprio pins: qt chains are independent; let the scheduler
        //  overlap qt k's exp2/pack with qt k+1's MFMAs)
#pragma unroll
        for (int qt = 0; qt < 4; ++qt) {
            f32x4 S[4];
#pragma unroll
            for (int k4 = 0; k4 < 4; ++k4) S[k4] = (f32x4){0.f, 0.f, 0.f, 0.f};

#pragma unroll
            for (int k4 = 0; k4 < 4; ++k4) {
                S[k4] = MFMAH(Qr[qt][0], kf[k4][0], S[k4]);
                S[k4] = MFMAH(Qr[qt][1], kf[k4][1], S[k4]);
            }

#pragma unroll
            for (int r = 0; r < 4; ++r) {
                const float p0 = fast_exp2(S[0][r]);
                const float p1 = fast_exp2(S[1][r]);
                const float p2 = fast_exp2(S[2][r]);
                const float p3 = fast_exp2(S[3][r]);
                uint2 pw;
                pw.x = pack_f16x2(p0, p1);
                pw.y = pack_f16x2(p2, p3);
                *(uint2*)&Pl[w][qt * 16 + lg * 4 + r][l15 * 4] = pw;
            }
        }

        // own-wave P writes must land before own-wave P reads
        asm volatile("s_waitcnt lgkmcnt(0)" ::: "memory");
        __builtin_amdgcn_sched_barrier(0);

        // ---- O += P V ; lsum += P @ 1  (permuted-kv order both sides) ----
        __builtin_amdgcn_s_setprio(1);
#pragma unroll
        for (int ks = 0; ks < 2; ++ks) {
            half8 Pf[4];
#pragma unroll
            for (int qt = 0; qt < 4; ++qt)
                Pf[qt] = *(const half8*)&Pl[w][qt * 16 + l15][ks * 32 + lg * 8];
#pragma unroll
            for (int dt = 0; dt < 4; ++dt) {
                const half8 Vfr = *(const half8*)&Vt[dt * 16 + l15][ks * 32 + lg * 8];
#pragma unroll
                for (int qt = 0; qt < 4; ++qt)
                    O[qt][dt] = MFMAH(Pf[qt], Vfr, O[qt][dt]);
            }
#pragma unroll
            for (int qt = 0; qt < 4; ++qt)
                accL[qt] = MFMAH(Pf[qt], vones, accL[qt]);
        }
        __builtin_amdgcn_s_setprio(0);
    }

    // ---- epilogue: lsum = accL (row sums, col-replicated); write f16 ----
#pragma unroll
    for (int qt = 0; qt < 4; ++qt)
#pragma unroll
        for (int r = 0; r < 4; ++r) {
            const float inv = 1.0f / accL[qt][r];
            const int row = qRow0 + qt * 16 + lg * 4 + r;
#pragma unroll
            for (int dt = 0; dt < 4; ++dt) {
                const float o = O[qt][dt][r] * inv;
                const size_t off = (size_t)row * 1024 + hc + dt * 16 + l15;
                Of[off] = __builtin_bit_cast(u16, (_Float16)o);
            }
        }
}

// ---------------------------------------------------------------------------
extern "C" void kernel_launch(void* const* d_in, const int* in_sizes, int n_in,
                              void* d_out, int out_size, void* d_ws, size_t ws_size,
                              hipStream_t stream)
{
    const float* x     = (const float*)d_in[0];
    const float* w_qkv = (const float*)d_in[1];
    const float* b_qkv = (const float*)d_in[2];
    const float* w_out = (const float*)d_in[3];
    const float* b_out = (const float*)d_in[4];
    float* out = (float*)d_out;

    const size_t PLANE = (size_t)BT_ROWS * DMODEL;
    u16* Qf  = (u16*)d_ws;                 // f16 Q (x log2e/8)
    u16* Kf  = Qf + PLANE;                 // f16 K
    u16* Vf  = Kf + PLANE;                 // f16 V
    u16* xF  = Vf + PLANE;                 // f16 x, later aliased as attn
    u16* aF  = xF;
    u16* wqkvF = xF + PLANE;               // f16 w_qkv
    u16* woutF = wqkvF + (size_t)3072 * 1024;   // f16 w_out

    // 1) fused fp32 -> f16 conversions (one launch)
    cvt_all<<<2048, 256, 0, stream>>>(x, w_qkv, w_out, xF, wqkvF, woutF);

    // 2) QKV projection -> Q(x log2e/8),K,V f16 planes
    gemm_nt_mfma<1><<<dim3(3072 / 128, BT_ROWS / 128), 256, 0, stream>>>(
        xF, wqkvF, b_qkv, nullptr, Qf, Kf, Vf);

    // 3) flash attention -> attn f16 plane
    flash_attn_mfma<<<dim3(512), 256, 0, stream>>>(Qf, Kf, Vf, aF);

    // 4) output projection -> fp32 out
    gemm_nt_mfma<0><<<dim3(DMODEL / 128, BT_ROWS / 128), 256, 0, stream>>>(
        aF, woutF, b_out, out, nullptr, nullptr, nullptr);
}

// Round 18
// 184.373 us; speedup vs baseline: 1.0123x; 1.0123x over previous
//
#include <hip/hip_runtime.h>
#include <hip/hip_bf16.h>

#define SEQLEN  2048
#define DMODEL  1024
#define NHEADS  16
#define BT_ROWS 8192

typedef __attribute__((ext_vector_type(8))) _Float16 half8;
typedef __attribute__((ext_vector_type(4))) _Float16 half4;
typedef __attribute__((ext_vector_type(2))) _Float16 half2v;
typedef __attribute__((ext_vector_type(4))) float f32x4;
typedef unsigned short u16;

#define MFMAH(A, B, C)  __builtin_amdgcn_mfma_f32_16x16x32_f16((A), (B), (C), 0, 0, 0)

static __device__ __forceinline__ float fast_exp2(float x) {
#if __has_builtin(__builtin_amdgcn_exp2f)
    return __builtin_amdgcn_exp2f(x);
#else
    return exp2f(x);
#endif
}

// async global->LDS 16B
typedef const __attribute__((address_space(1))) unsigned int* gas_t;
typedef __attribute__((address_space(3))) unsigned int* las_t;
static __device__ __forceinline__ void gld16(const void* g, void* l) {
    __builtin_amdgcn_global_load_lds((gas_t)g, (las_t)l, 16, 0, 0);
}

// pack two f32 -> one u32 of 2 x f16 (RTZ)
static __device__ __forceinline__ unsigned pack_f16x2(float a, float b) {
    return __builtin_bit_cast(unsigned, __builtin_amdgcn_cvt_pkrtz(a, b));
}

// ---------------------------------------------------------------------------
// fused fp32 -> f16 conversion of x, w_qkv, w_out (one launch)
// ---------------------------------------------------------------------------
#define N4_X  (BT_ROWS * DMODEL / 4)          // 2097152
#define N4_WQ (3072 * 1024 / 4)               // 786432
#define N4_WO (1024 * 1024 / 4)               // 262144

__global__ __launch_bounds__(256)
void cvt_all(const float* __restrict__ x, const float* __restrict__ wq,
             const float* __restrict__ wo, u16* __restrict__ xF,
             u16* __restrict__ wqF, u16* __restrict__ woF)
{
    const int total = N4_X + N4_WQ + N4_WO;
    int i = blockIdx.x * 256 + threadIdx.x;
    const int stride = gridDim.x * 256;
    for (; i < total; i += stride) {
        const float* src;
        u16* dst;
        int idx;
        if (i < N4_X)               { src = x;  dst = xF;  idx = i; }
        else if (i < N4_X + N4_WQ)  { src = wq; dst = wqF; idx = i - N4_X; }
        else                        { src = wo; dst = woF; idx = i - N4_X - N4_WQ; }
        const float4 v = ((const float4*)src)[idx];
        const float f[4] = {v.x, v.y, v.z, v.w};
        ushort4 h4;
        u16 hh[4];
#pragma unroll
        for (int j = 0; j < 4; ++j)
            hh[j] = __builtin_bit_cast(u16, (_Float16)f[j]);
        h4.x = hh[0]; h4.y = hh[1]; h4.z = hh[2]; h4.w = hh[3];
        *(ushort4*)(dst + (size_t)idx * 4) = h4;
    }
}

// ---------------------------------------------------------------------------
// f16 MFMA GEMM — m97 fragment structure + T4 counted-vmcnt pipeline,
// now 3-DEEP prefetch (tiles kt+1, kt+2 in flight across barriers) and
// XCD-aware 1D block swizzle (same-A-row blocks grouped per XCD: 8 complete
// row panels = 2 MB per XCD L2).
// Ordering proof (3-deep, per wave; 4 gld16 per stage):
//  - tile t (buf p=t%3) read between barrier1(t) and barrier2(t);
//  - buf p overwritten only by stage(t+3), issued after barrier2(t);
//  - stage(t+3) completion enforced at barrier1(t+3): in-flight there =
//    tiles t+3,t+4,t+5 = 12 loads; vmcnt(8) retires the oldest 4 (= t+3).
//  Tail: kt<=29 -> vmcnt(8); kt==30 -> vmcnt(4); kt==31 -> vmcnt(0).
//  lgkmcnt(0)+sched_barrier(0) before barrier2 (rule 18).
// MODE 0: fp32 C (+bias). MODE 1: Q(x log2e/8),K,V f16 planes.
// ---------------------------------------------------------------------------
template<int MODE, int NX, int NBLK>
__global__ __launch_bounds__(256)
void gemm_nt_mfma(const u16* __restrict__ Af, const u16* __restrict__ Bf,
                  const float* __restrict__ bias, float* __restrict__ Cf,
                  u16* __restrict__ Pq, u16* __restrict__ Pk,
                  u16* __restrict__ Pv)
{
    __shared__ _Float16 Ah[3][128 * 32];
    __shared__ _Float16 Bh[3][128 * 32];

    const int tid  = threadIdx.x;
    const int lane = tid & 63;
    const int w    = tid >> 6;
    const int l15  = lane & 15;
    const int lg   = lane >> 4;
    const int wm   = w & 1;
    const int wn   = w >> 1;

    // XCD swizzle: consecutive swz on one XCD -> consecutive x, same y row
    const int l    = blockIdx.x;
    const int swz  = (l & 7) * (NBLK / 8) + (l >> 3);
    const int rowBase = (swz / NX) * 128;
    const int colBase = (swz % NX) * 128;

    const int srow = lane >> 2;
    const int sc   = lane & 3;

    f32x4 acc[4][4];
#pragma unroll
    for (int m = 0; m < 4; ++m)
#pragma unroll
        for (int n = 0; n < 4; ++n) acc[m][n] = (f32x4){0.f, 0.f, 0.f, 0.f};

    auto stage = [&](int kt) {
        const int p  = kt % 3;
        const int k0 = kt * 32;
#pragma unroll
        for (int i = 0; i < 2; ++i) {
            const int slab = w * 2 + i;
            const int row  = slab * 16 + srow;
            const int gc   = sc ^ ((row >> 1) & 3);
            const size_t aoff = (size_t)(rowBase + row) * 1024 + k0 + gc * 8;
            const size_t boff = (size_t)(colBase + row) * 1024 + k0 + gc * 8;
            gld16(Af + aoff, &Ah[p][slab * 512]);
            gld16(Bf + boff, &Bh[p][slab * 512]);
        }
    };

    stage(0);
    stage(1);
    stage(2);

    for (int kt = 0; kt < 32; ++kt) {
        const int p = kt % 3;

        // barrier 1: my tile-kt loads done (counted; kt+1,kt+2 in flight)
        if (kt <= 29) {
            asm volatile("s_waitcnt vmcnt(8)" ::: "memory");
        } else if (kt == 30) {
            asm volatile("s_waitcnt vmcnt(4)" ::: "memory");
        } else {
            asm volatile("s_waitcnt vmcnt(0)" ::: "memory");
        }
        __builtin_amdgcn_s_barrier();

        half8 afh[4], bfh[4];
#pragma unroll
        for (int m = 0; m < 4; ++m) {
            const int row = wm * 64 + m * 16 + l15;
            const int cR  = lg ^ ((row >> 1) & 3);
            afh[m] = *(const half8*)&Ah[p][row * 32 + cR * 8];
        }
#pragma unroll
        for (int n = 0; n < 4; ++n) {
            const int row = wn * 64 + n * 16 + l15;
            const int cR  = lg ^ ((row >> 1) & 3);
            bfh[n] = *(const half8*)&Bh[p][row * 32 + cR * 8];
        }

        // frags in regs before anyone overwrites buf p (rule 18 fence)
        asm volatile("s_waitcnt lgkmcnt(0)" ::: "memory");
        __builtin_amdgcn_sched_barrier(0);
        __builtin_amdgcn_s_barrier();     // barrier 2: all waves' reads done

        if (kt < 29) stage(kt + 3);       // overwrite buf p for tile kt+3

        __builtin_amdgcn_s_setprio(1);
#pragma unroll
        for (int m = 0; m < 4; ++m)
#pragma unroll
            for (int n = 0; n < 4; ++n)
                acc[m][n] = MFMAH(afh[m], bfh[n], acc[m][n]);
        __builtin_amdgcn_s_setprio(0);
    }

    float bv[4];
#pragma unroll
    for (int n = 0; n < 4; ++n)
        bv[n] = bias[colBase + wn * 64 + n * 16 + l15];

    if constexpr (MODE == 0) {
#pragma unroll
        for (int m = 0; m < 4; ++m)
#pragma unroll
            for (int n = 0; n < 4; ++n) {
                const int col = colBase + wn * 64 + n * 16 + l15;
#pragma unroll
                for (int r = 0; r < 4; ++r) {
                    const int row = rowBase + wm * 64 + m * 16 + lg * 4 + r;
                    Cf[(size_t)row * 1024 + col] = acc[m][n][r] + bv[n];
                }
            }
    } else {
        const int comp = colBase >> 10;                  // 0=Q 1=K 2=V
        const float scale = (comp == 0) ? (0.125f * 1.44269504f) : 1.0f;
        u16* hp = (comp == 0) ? Pq : ((comp == 1) ? Pk : Pv);
        const int colc0 = colBase & 1023;
#pragma unroll
        for (int m = 0; m < 4; ++m)
#pragma unroll
            for (int n = 0; n < 4; ++n) {
                const int col = colc0 + wn * 64 + n * 16 + l15;
#pragma unroll
                for (int r = 0; r < 4; ++r) {
                    const int row = rowBase + wm * 64 + m * 16 + lg * 4 + r;
                    const float v = (acc[m][n][r] + bv[n]) * scale;
                    hp[(size_t)row * 1024 + col] =
                        __builtin_bit_cast(u16, (_Float16)v);
                }
            }
    }
}

// ---------------------------------------------------------------------------
// f16 MFMA flash attention — R10/R15 proven structure (green R17 file,
// byte-identical this round). 803 TF; structurally converged.
// ---------------------------------------------------------------------------
__global__ __launch_bounds__(256, 2)
void flash_attn_mfma(const u16* __restrict__ Qf, const u16* __restrict__ Kf,
                     const u16* __restrict__ Vf, u16* __restrict__ Of)
{
    __shared__ __align__(16) _Float16 Kh[64 * 64];
    __shared__ __align__(16) _Float16 Vt[64][72];
    __shared__ __align__(16) _Float16 Pl[4][64][72];

    const int tid  = threadIdx.x;
    const int lane = tid & 63;
    const int w    = tid >> 6;
    const int l15  = lane & 15;
    const int lg   = lane >> 4;

    // 512 blocks: 8 XCDs x 64 -> 8 heads x 8 q-blocks per XCD
    const int raw = blockIdx.x;
    const int swz = (raw & 7) * 64 + (raw >> 3);
    const int bh  = swz >> 3;          // 0..63
    const int qb  = swz & 7;           // 0..7
    const int b   = bh >> 4;
    const int h   = bh & 15;

    const int qRow0 = b * SEQLEN + qb * 256 + w * 64;   // wave's q base
    const int kRowB = b * SEQLEN;
    const int hc    = h * 64;

    // ---- Q fragments (4 qt tiles of 16 rows), already scaled ----
    half8 Qr[4][2];
#pragma unroll
    for (int qt = 0; qt < 4; ++qt)
#pragma unroll
        for (int g = 0; g < 2; ++g) {
            const size_t off = (size_t)(qRow0 + qt * 16 + l15) * 1024
                             + hc + g * 32 + lg * 8;
            Qr[qt][g] = *(const half8*)(Qf + off);
        }

    f32x4 O[4][4];
    f32x4 accL[4];                     // lsum via ones-MFMA
#pragma unroll
    for (int qt = 0; qt < 4; ++qt) {
        accL[qt] = (f32x4){0.f, 0.f, 0.f, 0.f};
#pragma unroll
        for (int dt = 0; dt < 4; ++dt) O[qt][dt] = (f32x4){0.f, 0.f, 0.f, 0.f};
    }
    half8 vones;
#pragma unroll
    for (int j = 0; j < 8; ++j) vones[j] = (_Float16)1.0f;

    // V loader: rows (kv0, kv0+16) share (kv&15) -> adjacent permuted cols
    const int vp  = tid & 31;
    const int kv0 = (vp & 15) | ((vp >> 4) << 5);     // {0..15} u {32..47}
    const int pcol = (kv0 & 15) * 4 + (kv0 >> 4);     // even; pair at +1
    const int d0  = (tid >> 5) * 8;                   // 0..56

    // staged-tile registers (live across compute: T14)
    half8 kreg[2], vreg0, vreg1;
    int krow[2], kcc[2];

    auto load_tile = [&](int kt) {
#pragma unroll
        for (int i = 0; i < 2; ++i) {
            const int s = tid + 256 * i;
            const int row = s >> 3;
            const int c   = s & 7;
            krow[i] = row; kcc[i] = c;
            const int gc = c ^ (row & 7);
            const size_t g = (size_t)(kRowB + kt * 64 + row) * 1024 + hc + gc * 8;
            kreg[i] = *(const half8*)(Kf + g);
        }
        const size_t g = (size_t)(kRowB + kt * 64 + kv0) * 1024 + hc + d0;
        vreg0 = *(const half8*)(Vf + g);
        vreg1 = *(const half8*)(Vf + g + (size_t)16 * 1024);
    };

    load_tile(0);

    for (int kt = 0; kt < SEQLEN / 64; ++kt) {
        __syncthreads();   // previous tile's LDS reads complete
#pragma unroll
        for (int i = 0; i < 2; ++i)
            *(half8*)&Kh[krow[i] * 64 + kcc[i] * 8] = kreg[i];
#pragma unroll
        for (int j = 0; j < 8; ++j) {
            half2v pv;
            pv[0] = vreg0[j]; pv[1] = vreg1[j];
            *(half2v*)&Vt[d0 + j][pcol] = pv;
        }
        __syncthreads();   // staging visible

        if (kt < SEQLEN / 64 - 1) load_tile(kt + 1);   // overlaps compute below

        // ---- K fragments once (shared across all 4 qt) ----
        half8 kf[4][2];
#pragma unroll
        for (int k4 = 0; k4 < 4; ++k4) {
            const int row = k4 * 16 + l15;
            const int swk = row & 7;
            kf[k4][0] = *(const half8*)&Kh[row * 64 + ((lg     ^ swk) * 8)];
            kf[k4][1] = *(const half8*)&Kh[row * 64 + (((4+lg) ^ swk) * 8)];
        }

        // ---- per qt: S = (Q*log2e/8)K^T, p = 2^S, pack, b64 store ----
#pragma unroll
        for (int qt = 0; qt < 4; ++qt) {
            f32x4 S[4];
#pragma unroll
            for (int k4 = 0; k4 < 4; ++k4) S[k4] = (f32x4){0.f, 0.f, 0.f, 0.f};

#pragma unroll
            for (int k4 = 0; k4 < 4; ++k4) {
                S[k4] = MFMAH(Qr[qt][0], kf[k4][0], S[k4]);
                S[k4] = MFMAH(Qr[qt][1], kf[k4][1], S[k4]);
            }

#pragma unroll
            for (int r = 0; r < 4; ++r) {
                const float p0 = fast_exp2(S[0][r]);
                const float p1 = fast_exp2(S[1][r]);
                const float p2 = fast_exp2(S[2][r]);
                const float p3 = fast_exp2(S[3][r]);
                uint2 pw;
                pw.x = pack_f16x2(p0, p1);
                pw.y = pack_f16x2(p2, p3);
                *(uint2*)&Pl[w][qt * 16 + lg * 4 + r][l15 * 4] = pw;
            }
        }

        // own-wave P writes must land before own-wave P reads
        asm volatile("s_waitcnt lgkmcnt(0)" ::: "memory");
        __builtin_amdgcn_sched_barrier(0);

        // ---- O += P V ; lsum += P @ 1  (permuted-kv order both sides) ----
        __builtin_amdgcn_s_setprio(1);
#pragma unroll
        for (int ks = 0; ks < 2; ++ks) {
            half8 Pf[4];
#pragma unroll
            for (int qt = 0; qt < 4; ++qt)
                Pf[qt] = *(const half8*)&Pl[w][qt * 16 + l15][ks * 32 + lg * 8];
#pragma unroll
            for (int dt = 0; dt < 4; ++dt) {
                const half8 Vfr = *(const half8*)&Vt[dt * 16 + l15][ks * 32 + lg * 8];
#pragma unroll
                for (int qt = 0; qt < 4; ++qt)
                    O[qt][dt] = MFMAH(Pf[qt], Vfr, O[qt][dt]);
            }
#pragma unroll
            for (int qt = 0; qt < 4; ++qt)
                accL[qt] = MFMAH(Pf[qt], vones, accL[qt]);
        }
        __builtin_amdgcn_s_setprio(0);
    }

    // ---- epilogue: lsum = accL (row sums, col-replicated); write f16 ----
#pragma unroll
    for (int qt = 0; qt < 4; ++qt)
#pragma unroll
        for (int r = 0; r < 4; ++r) {
            const float inv = 1.0f / accL[qt][r];
            const int row = qRow0 + qt * 16 + lg * 4 + r;
#pragma unroll
            for (int dt = 0; dt < 4; ++dt) {
                const float o = O[qt][dt][r] * inv;
                const size_t off = (size_t)row * 1024 + hc + dt * 16 + l15;
                Of[off] = __builtin_bit_cast(u16, (_Float16)o);
            }
        }
}

// ---------------------------------------------------------------------------
extern "C" void kernel_launch(void* const* d_in, const int* in_sizes, int n_in,
                              void* d_out, int out_size, void* d_ws, size_t ws_size,
                              hipStream_t stream)
{
    const float* x     = (const float*)d_in[0];
    const float* w_qkv = (const float*)d_in[1];
    const float* b_qkv = (const float*)d_in[2];
    const float* w_out = (const float*)d_in[3];
    const float* b_out = (const float*)d_in[4];
    float* out = (float*)d_out;

    const size_t PLANE = (size_t)BT_ROWS * DMODEL;
    u16* Qf  = (u16*)d_ws;                 // f16 Q (x log2e/8)
    u16* Kf  = Qf + PLANE;                 // f16 K
    u16* Vf  = Kf + PLANE;                 // f16 V
    u16* xF  = Vf + PLANE;                 // f16 x, later aliased as attn
    u16* aF  = xF;
    u16* wqkvF = xF + PLANE;               // f16 w_qkv
    u16* woutF = wqkvF + (size_t)3072 * 1024;   // f16 w_out

    // 1) fused fp32 -> f16 conversions (one launch)
    cvt_all<<<2048, 256, 0, stream>>>(x, w_qkv, w_out, xF, wqkvF, woutF);

    // 2) QKV projection -> Q(x log2e/8),K,V f16 planes  (1536 = 24 x 64 tiles)
    gemm_nt_mfma<1, 24, 1536><<<1536, 256, 0, stream>>>(
        xF, wqkvF, b_qkv, nullptr, Qf, Kf, Vf);

    // 3) flash attention -> attn f16 plane
    flash_attn_mfma<<<dim3(512), 256, 0, stream>>>(Qf, Kf, Vf, aF);

    // 4) output projection -> fp32 out  (512 = 8 x 64 tiles)
    gemm_nt_mfma<0, 8, 512><<<512, 256, 0, stream>>>(
        aF, woutF, b_out, out, nullptr, nullptr, nullptr);
}